// Round 5
// baseline (106.674 us; speedup 1.0000x reference)
//
#include <hip/hip_runtime.h>
#include <hip/hip_bf16.h>

#define N_Q    20
#define DIM    (1 << N_Q)      // 1048576
#define BATCH  4
#define NGATES 19
#define L2OFF  117             // 6n-3 : second xyz layer offset

typedef float2 c32;
typedef __attribute__((ext_vector_type(8))) short short8;
typedef __attribute__((ext_vector_type(4))) float f32x4;
typedef __attribute__((ext_vector_type(4))) unsigned int u32x4;

__device__ __forceinline__ c32 cmul(c32 a, c32 b) {
    return make_float2(fmaf(a.x, b.x, -a.y * b.y), fmaf(a.x, b.y, a.y * b.x));
}
__device__ __forceinline__ c32 cmadd(c32 acc, c32 a, c32 b) {
    acc.x = fmaf(a.x, b.x, fmaf(-a.y, b.y, acc.x));
    acc.y = fmaf(a.x, b.y, fmaf(a.y, b.x, acc.y));
    return acc;
}
__device__ __forceinline__ unsigned short f2bf(float f) {
    union { float f; unsigned u; } v; v.f = f;
    unsigned r = v.u + 0x7FFFu + ((v.u >> 16) & 1u);
    return (unsigned short)(r >> 16);
}
__device__ __forceinline__ void gll16(const void* g, void* l) {
    __builtin_amdgcn_global_load_lds((const __attribute__((address_space(1))) void*)g,
                                     (__attribute__((address_space(3))) void*)l, 16, 0, 0);
}

__device__ void mm2(const c32 A[2][2], const c32 B[2][2], c32 C[2][2]) {
    for (int i = 0; i < 2; i++)
        for (int j = 0; j < 2; j++) {
            c32 s = make_float2(0.f, 0.f);
            for (int k = 0; k < 2; k++) s = cmadd(s, A[i][k], B[k][j]);
            C[i][j] = s;
        }
}
__device__ void mm4(const c32 A[4][4], const c32 B[4][4], c32 C[4][4]) {
    for (int i = 0; i < 4; i++)
        for (int j = 0; j < 4; j++) {
            c32 s = make_float2(0.f, 0.f);
            for (int k = 0; k < 4; k++) s = cmadd(s, A[i][k], B[k][j]);
            C[i][j] = s;
        }
}
__device__ void single_u(const float* w, int base, c32 U[2][2]) {
    const float WM = 0.63245553203367586640f;  // sqrt(2/5)
    float hx = w[base] * WM * 0.5f, hy = w[base + 1] * WM * 0.5f, hz = w[base + 2] * WM * 0.5f;
    float cx = cosf(hx), sx = sinf(hx);
    float cy = cosf(hy), sy = sinf(hy);
    float cz = cosf(hz), sz = sinf(hz);
    c32 RX[2][2] = {{{cx, 0.f}, {0.f, -sx}}, {{0.f, -sx}, {cx, 0.f}}};
    c32 RY[2][2] = {{{cy, 0.f}, {-sy, 0.f}}, {{sy, 0.f}, {cy, 0.f}}};
    c32 RZ[2][2] = {{{cz, -sz}, {0.f, 0.f}}, {{0.f, 0.f}, {cz, sz}}};
    c32 T[2][2];
    mm2(RY, RX, T);
    mm2(RZ, T, U);
}
__device__ void kron22(const c32 A[2][2], const c32 B[2][2], c32 K[4][4]) {
    for (int i = 0; i < 2; i++)
        for (int j = 0; j < 2; j++)
            for (int k = 0; k < 2; k++)
                for (int l = 0; l < 2; l++)
                    K[i * 2 + j][k * 2 + l] = cmul(A[i][k], B[j][l]);
}

// Build the 19 fused 4x4 staircase gates (round-0 derivation).
__global__ void build_gates(const float* __restrict__ w, c32* __restrict__ G) {
    int q = threadIdx.x;
    if (q >= NGATES) return;
    const float WM = 0.63245553203367586640f;
    float hx = w[60 + 3 * q] * WM * 0.5f;
    float hy = w[61 + 3 * q] * WM * 0.5f;
    float hz = w[62 + 3 * q] * WM * 0.5f;
    float cx = cosf(hx), sx = sinf(hx);
    float cy = cosf(hy), sy = sinf(hy);
    float cz = cosf(hz), sz = sinf(hz);
    c32 RXX[4][4], RYY[4][4], RZZ[4][4];
    for (int i = 0; i < 4; i++)
        for (int j = 0; j < 4; j++) {
            RXX[i][j] = make_float2(0.f, 0.f);
            RYY[i][j] = make_float2(0.f, 0.f);
            RZZ[i][j] = make_float2(0.f, 0.f);
        }
    for (int i = 0; i < 4; i++) {
        RXX[i][i]     = make_float2(cx, 0.f);
        RXX[i][3 - i] = make_float2(0.f, -sx);
        RYY[i][i]     = make_float2(cy, 0.f);
    }
    RYY[0][3] = make_float2(0.f,  sy);
    RYY[1][2] = make_float2(0.f, -sy);
    RYY[2][1] = make_float2(0.f, -sy);
    RYY[3][0] = make_float2(0.f,  sy);
    RZZ[0][0] = make_float2(cz, -sz);
    RZZ[1][1] = make_float2(cz,  sz);
    RZZ[2][2] = make_float2(cz,  sz);
    RZZ[3][3] = make_float2(cz, -sz);
    c32 T[4][4], M[4][4];
    mm4(RYY, RXX, T);
    mm4(RZZ, T, M);

    c32 I2m[2][2] = {{{1.f, 0.f}, {0.f, 0.f}}, {{0.f, 0.f}, {1.f, 0.f}}};
    c32 Ua[2][2], Ub[2][2], Pre[4][4], Post[4][4];
    if (q == 0) {
        single_u(w, 0, Ua);
        single_u(w, 3, Ub);
        kron22(Ua, Ub, Pre);
    } else {
        single_u(w, 3 * (q + 1), Ub);
        kron22(I2m, Ub, Pre);
    }
    if (q == NGATES - 1) {
        single_u(w, L2OFF + 3 * 18, Ua);
        single_u(w, L2OFF + 3 * 19, Ub);
        kron22(Ua, Ub, Post);
    } else {
        single_u(w, L2OFF + 3 * q, Ua);
        kron22(Ua, I2m, Post);
    }
    c32 T2[4][4], Gq[4][4];
    mm4(M, Pre, T2);
    mm4(Post, T2, Gq);
    for (int i = 0; i < 4; i++)
        for (int j = 0; j < 4; j++)
            G[q * 16 + i * 4 + j] = Gq[i][j];
}

__device__ __forceinline__ void apply4(const c32* g, c32& x0, c32& x1, c32& x2, c32& x3) {
    c32 r0 = cmul(g[0],  x0); r0 = cmadd(r0, g[1],  x1); r0 = cmadd(r0, g[2],  x2); r0 = cmadd(r0, g[3],  x3);
    c32 r1 = cmul(g[4],  x0); r1 = cmadd(r1, g[5],  x1); r1 = cmadd(r1, g[6],  x2); r1 = cmadd(r1, g[7],  x3);
    c32 r2 = cmul(g[8],  x0); r2 = cmadd(r2, g[9],  x1); r2 = cmadd(r2, g[10], x2); r2 = cmadd(r2, g[11], x3);
    c32 r3 = cmul(g[12], x0); r3 = cmadd(r3, g[13], x1); r3 = cmadd(r3, g[14], x2); r3 = cmadd(r3, g[15], x3);
    x0 = r0; x1 = r1; x2 = r2; x3 = r3;
}
__device__ __forceinline__ void load_gate(const c32* __restrict__ gp, c32 g[16]) {
#pragma unroll
    for (int k = 0; k < 16; k++) g[k] = gp[k];
}
template <int LO>
__device__ __forceinline__ void gate_on32(c32 v[32], const c32 g[16]) {
#pragma unroll
    for (int m = 0; m < 8; ++m) {
        const int j0 = ((m >> LO) << (LO + 2)) | (m & ((1 << LO) - 1));
        const int s = 1 << LO;
        apply4(g, v[j0], v[j0 + s], v[j0 + 2 * s], v[j0 + 3 * s]);
    }
}
template <int LO>
__device__ __forceinline__ void gate_on16(c32* v, const c32 g[16]) {
#pragma unroll
    for (int m = 0; m < 4; ++m) {
        const int j0 = ((m >> LO) << (LO + 2)) | (m & ((1 << LO) - 1));
        const int s = 1 << LO;
        apply4(g, v[j0], v[j0 + s], v[j0 + 2 * s], v[j0 + 3 * s]);
    }
}

// XOR swizzle for 8192-c32 LDS exchanges (verified <=4-way for all patterns used).
#define SIDX(l) ((l) ^ ((((l) >> 5) & 15)))

// Pass A2: gates 0..6 (psi bits 19..12). State = [256 rows = bits 19..12][4096 cols].
// Block: 256 rows x 32 cols. float4-staged x loads -> swizzled f32 LDS -> gather.
__global__ __launch_bounds__(256) void pass_a2(const float* __restrict__ x,
                                               c32* __restrict__ psi,
                                               const c32* __restrict__ Gall) {
    __shared__ __align__(16) char smem[65536];
    float* xs = (float*)smem;        // [256][32] f32, 16B-slot swizzled (32 KB)
    c32* s = (c32*)smem;             // 8192 c32 exchange view (64 KB)
    int b = blockIdx.x >> 7;
    int c0 = (blockIdx.x & 127) << 5;
    const float* xp = x + ((size_t)b << 20) + c0;
    c32* pp = psi + ((size_t)b << 20) + c0;
    int t = threadIdx.x;
    // stage x tile: 2048 float4 (16 B/lane, 8 x 128B segments per inst)
#pragma unroll
    for (int i = 0; i < 8; ++i) {
        int f4 = t + (i << 8);
        int row = f4 >> 3, sl = f4 & 7;
        float4 v = *reinterpret_cast<const float4*>(xp + (size_t)row * 4096 + sl * 4);
        reinterpret_cast<float4*>(xs)[row * 8 + (sl ^ (row & 7))] = v;
    }
    __syncthreads();
    int col = t & 31, rlow = t >> 5;          // rlow = row bits 2..0 (global 14..12)
    c32 v[32], g[16];
#pragma unroll
    for (int j = 0; j < 32; ++j) {
        int row = (j << 3) | rlow;
        float re = xs[row * 32 + ((((col >> 2) ^ (row & 7)) << 2) | (col & 3))];
        v[j] = make_float2(re, 0.f);
    }
    __syncthreads();                           // xs reads done before c32 reuse
    load_gate(Gall + 0 * 16, g);  gate_on32<3>(v, g);
    load_gate(Gall + 1 * 16, g);  gate_on32<2>(v, g);
    load_gate(Gall + 2 * 16, g);  gate_on32<1>(v, g);
    load_gate(Gall + 3 * 16, g);  gate_on32<0>(v, g);
#pragma unroll
    for (int j = 0; j < 32; ++j) {
        int l = ((((j << 3) | rlow) << 5)) | col;
        s[SIDX(l)] = v[j];
    }
    __syncthreads();
    int rhi = t >> 5;                          // row bits 6..4
#pragma unroll
    for (int rtop = 0; rtop < 2; ++rtop)
#pragma unroll
        for (int j = 0; j < 16; ++j) {
            int row = (rtop << 7) | (rhi << 4) | j;
            int l = (row << 5) | col;
            v[rtop * 16 + j] = s[SIDX(l)];
        }
    load_gate(Gall + 4 * 16, g);  gate_on16<2>(v, g);  gate_on16<2>(v + 16, g);
    load_gate(Gall + 5 * 16, g);  gate_on16<1>(v, g);  gate_on16<1>(v + 16, g);
    load_gate(Gall + 6 * 16, g);  gate_on16<0>(v, g);  gate_on16<0>(v + 16, g);
#pragma unroll
    for (int rtop = 0; rtop < 2; ++rtop)
#pragma unroll
        for (int j = 0; j < 16; ++j) {
            int row = (rtop << 7) | (rhi << 4) | j;
            pp[(size_t)row * 4096 + col] = v[rtop * 16 + j];
        }
}

// Pass B2: gates 7..18 (psi bits 12..0). Block = one 8192-amp contiguous chunk.
// 3 register phases, 2 LDS exchanges; writes planar bf16 [t][a] (Brt, Bit).
__global__ __launch_bounds__(256) void pass_b2(const c32* __restrict__ psi,
                                               unsigned short* __restrict__ Brt,
                                               unsigned short* __restrict__ Bit,
                                               const c32* __restrict__ Gall) {
    __shared__ c32 s[8192];
    int b = blockIdx.x >> 7;
    int chunk = blockIdx.x & 127;
    const c32* pp = psi + ((size_t)b << 20) + ((size_t)chunk << 13);
    int t = threadIdx.x;
    c32 v[32], g[16];
#pragma unroll
    for (int j = 0; j < 32; ++j) v[j] = pp[(j << 8) | t];
    load_gate(Gall + 7 * 16, g);   gate_on32<3>(v, g);
    load_gate(Gall + 8 * 16, g);   gate_on32<2>(v, g);
    load_gate(Gall + 9 * 16, g);   gate_on32<1>(v, g);
    load_gate(Gall + 10 * 16, g);  gate_on32<0>(v, g);
#pragma unroll
    for (int j = 0; j < 32; ++j) { int l = (j << 8) | t; s[SIDX(l)] = v[j]; }
    __syncthreads();
    int hi2 = (t >> 4) << 9, lo2 = t & 15;
#pragma unroll
    for (int j = 0; j < 32; ++j) { int l = hi2 | (j << 4) | lo2; v[j] = s[SIDX(l)]; }
    load_gate(Gall + 11 * 16, g);  gate_on32<3>(v, g);
    load_gate(Gall + 12 * 16, g);  gate_on32<2>(v, g);
    load_gate(Gall + 13 * 16, g);  gate_on32<1>(v, g);
    load_gate(Gall + 14 * 16, g);  gate_on32<0>(v, g);
    __syncthreads();
#pragma unroll
    for (int j = 0; j < 32; ++j) { int l = hi2 | (j << 4) | lo2; s[SIDX(l)] = v[j]; }
    __syncthreads();
#pragma unroll
    for (int j = 0; j < 32; ++j) { int l = (t << 5) | j; v[j] = s[SIDX(l)]; }
    load_gate(Gall + 15 * 16, g);  gate_on32<3>(v, g);
    load_gate(Gall + 16 * 16, g);  gate_on32<2>(v, g);
    load_gate(Gall + 17 * 16, g);  gate_on32<1>(v, g);
    load_gate(Gall + 18 * 16, g);  gate_on32<0>(v, g);
    size_t off = ((size_t)b << 20) + ((size_t)chunk << 13) + ((size_t)t << 5);
#pragma unroll
    for (int p = 0; p < 4; ++p) {
        unsigned short rr[8], ri[8];
#pragma unroll
        for (int i = 0; i < 8; ++i) {
            rr[i] = f2bf(v[8 * p + i].x);
            ri[i] = f2bf(v[8 * p + i].y);
        }
        *reinterpret_cast<float4*>(Brt + off + 8 * p) = *reinterpret_cast<float4*>(rr);
        *reinterpret_cast<float4*>(Bit + off + 8 * p) = *reinterpret_cast<float4*>(ri);
    }
}

// bf16 transpose: B[t][a] -> A[a][t] for both planes, merged as u32 in LDS.
__global__ __launch_bounds__(256) void bt_t(const unsigned short* __restrict__ Brt,
                                            const unsigned short* __restrict__ Bit,
                                            unsigned short* __restrict__ Art,
                                            unsigned short* __restrict__ Ait) {
    __shared__ unsigned lds32[64 * 66];
    int b  = blockIdx.z;
    int t0 = blockIdx.x * 64;
    int a0 = blockIdx.y * 64;
    size_t gb = (size_t)b << 20;
#pragma unroll
    for (int h = 0; h < 2; ++h) {
        int p = threadIdx.x + h * 256;
        int r = p >> 3, cq = p & 7;
        size_t src = gb + (size_t)(t0 + r) * 1024 + a0 + cq * 8;
        float4 fr = *reinterpret_cast<const float4*>(Brt + src);
        float4 fi = *reinterpret_cast<const float4*>(Bit + src);
        const unsigned short* ur = reinterpret_cast<const unsigned short*>(&fr);
        const unsigned short* ui = reinterpret_cast<const unsigned short*>(&fi);
#pragma unroll
        for (int i = 0; i < 8; ++i)
            lds32[r * 66 + cq * 8 + i] = (unsigned)ur[i] | ((unsigned)ui[i] << 16);
    }
    __syncthreads();
#pragma unroll
    for (int h = 0; h < 2; ++h) {
        int q = threadIdx.x + h * 256;
        int a = q >> 3, tq = q & 7;
        unsigned short rr[8], ri[8];
#pragma unroll
        for (int i = 0; i < 8; ++i) {
            unsigned w = lds32[(tq * 8 + i) * 66 + a];
            rr[i] = (unsigned short)(w & 0xFFFF);
            ri[i] = (unsigned short)(w >> 16);
        }
        size_t dst = gb + (size_t)(a0 + a) * 1024 + t0 + tq * 8;
        *reinterpret_cast<float4*>(Art + dst) = *reinterpret_cast<float4*>(rr);
        *reinterpret_cast<float4*>(Ait + dst) = *reinterpret_cast<float4*>(ri);
    }
}

// gram_mfma2: global_load_lds staging into XOR-swizzled linear LDS, double-buffered,
// one __syncthreads per K-step. Re = Ar.Br^T + Ai.Bi^T ; Im = Ai.Br^T + (-Ar).Bi^T.
// LDS: 2 bufs x 4 arrays {aR,aI,cR,cI} x [64 rows][8 slots of 16B], slot' = slot ^ (row&7).
__device__ __forceinline__ void stage_panel(const unsigned short* __restrict__ sp, size_t gb,
                                            int prow, int kt, unsigned short* dst, int lane) {
    int srow = lane >> 3, sslot = lane & 7;
#pragma unroll
    for (int i = 0; i < 8; ++i) {
        int r = (i << 3) | srow;
        int sl = sslot ^ srow;             // (r&7) == srow
        const unsigned short* gp = sp + gb + ((size_t)(prow + r) << 10) + kt * 64 + sl * 8;
        gll16(gp, dst + i * 512);          // linear dest: base + lane*16B
    }
}
__global__ __launch_bounds__(256) void gram_mfma2(const unsigned short* __restrict__ Art,
                                                  const unsigned short* __restrict__ Ait,
                                                  float2* __restrict__ out) {
    __shared__ unsigned short lds[2][4][4096];   // 64 KB
    int b = blockIdx.y;
    int rem = blockIdx.x;                        // triangular decode, ia <= ic
    int ia = 0;
    while (rem >= 16 - ia) { rem -= 16 - ia; ++ia; }
    int ic = ia + rem;
    int a0 = ia * 64, c0 = ic * 64;
    int lane = threadIdx.x & 63, w = threadIdx.x >> 6;
    int wr = (w >> 1) * 32, wc = (w & 1) * 32;
    const unsigned short* sp = (w & 1) ? Ait : Art;   // wave stages one array
    int prow = (w < 2) ? a0 : c0;
    size_t gb = (size_t)b << 20;

    f32x4 accRe[2][2], accIm[2][2];
#pragma unroll
    for (int m = 0; m < 2; m++)
#pragma unroll
        for (int n = 0; n < 2; n++) { accRe[m][n] = (f32x4)0.f; accIm[m][n] = (f32x4)0.f; }

    stage_panel(sp, gb, prow, 0, &lds[0][w][0], lane);
    __syncthreads();
    for (int kt = 0; kt < 16; ++kt) {
        int cur = kt & 1;
        if (kt < 15) stage_panel(sp, gb, prow, kt + 1, &lds[cur ^ 1][w][0], lane);
#pragma unroll
        for (int kk = 0; kk < 2; ++kk) {
            int sbase = kk * 4 + (lane >> 4);    // 16B-slot index 0..7
            short8 ar[2], ai[2], br[2], bi[2];
#pragma unroll
            for (int m = 0; m < 2; m++) {
                int r = wr + m * 16 + (lane & 15);
                int off = r * 64 + ((sbase ^ (r & 7)) << 3);
                ar[m] = *reinterpret_cast<const short8*>(&lds[cur][0][off]);
                ai[m] = *reinterpret_cast<const short8*>(&lds[cur][1][off]);
            }
#pragma unroll
            for (int n = 0; n < 2; n++) {
                int r = wc + n * 16 + (lane & 15);
                int off = r * 64 + ((sbase ^ (r & 7)) << 3);
                br[n] = *reinterpret_cast<const short8*>(&lds[cur][2][off]);
                bi[n] = *reinterpret_cast<const short8*>(&lds[cur][3][off]);
            }
#pragma unroll
            for (int m = 0; m < 2; m++) {
                u32x4 tn = *reinterpret_cast<u32x4*>(&ar[m]) ^ 0x80008000u;
                short8 arn = *reinterpret_cast<short8*>(&tn);
#pragma unroll
                for (int n = 0; n < 2; n++) {
                    accRe[m][n] = __builtin_amdgcn_mfma_f32_16x16x32_bf16(ar[m],  br[n], accRe[m][n], 0, 0, 0);
                    accRe[m][n] = __builtin_amdgcn_mfma_f32_16x16x32_bf16(ai[m],  bi[n], accRe[m][n], 0, 0, 0);
                    accIm[m][n] = __builtin_amdgcn_mfma_f32_16x16x32_bf16(ai[m],  br[n], accIm[m][n], 0, 0, 0);
                    accIm[m][n] = __builtin_amdgcn_mfma_f32_16x16x32_bf16(arn,    bi[n], accIm[m][n], 0, 0, 0);
                }
            }
        }
        __syncthreads();   // drains this iter's gll (vmcnt0) + ds reads (lgkmcnt0)
    }
    // C/D layout: col = lane&15, row = (lane>>4)*4 + reg
    size_t ob = (size_t)b << 20;
#pragma unroll
    for (int m = 0; m < 2; m++)
#pragma unroll
        for (int n = 0; n < 2; n++)
#pragma unroll
            for (int r = 0; r < 4; r++) {
                int a = a0 + wr + m * 16 + (lane >> 4) * 4 + r;
                int c = c0 + wc + n * 16 + (lane & 15);
                float re = accRe[m][n][r];
                float im = accIm[m][n][r];
                out[ob + ((size_t)a << 10) + c] = make_float2(re, im);
                if (ia != ic)
                    out[ob + ((size_t)c << 10) + a] = make_float2(re, -im);
            }
}

extern "C" void kernel_launch(void* const* d_in, const int* in_sizes, int n_in,
                              void* d_out, int out_size, void* d_ws, size_t ws_size,
                              hipStream_t stream) {
    const float* x = (const float*)d_in[0];
    const float* weight = (const float*)d_in[1];
    const size_t psiBytes = (size_t)BATCH * DIM * sizeof(c32);       // 32 MB
    c32* psi = (c32*)d_ws;
    c32* G = (c32*)((char*)d_ws + psiBytes);
    unsigned short* Brt = (unsigned short*)((char*)d_ws + psiBytes + 65536);
    unsigned short* Bit = Brt + (size_t)BATCH * DIM;
    unsigned short* Art = Bit + (size_t)BATCH * DIM;
    unsigned short* Ait = Art + (size_t)BATCH * DIM;

    build_gates<<<1, 64, 0, stream>>>(weight, G);
    pass_a2<<<BATCH * 128, 256, 0, stream>>>(x, psi, G);            // gates 0..6
    pass_b2<<<BATCH * 128, 256, 0, stream>>>(psi, Brt, Bit, G);     // gates 7..18 -> bf16 [t][a]
    bt_t<<<dim3(16, 16, BATCH), 256, 0, stream>>>(Brt, Bit, Art, Ait);
    gram_mfma2<<<dim3(136, BATCH), 256, 0, stream>>>(Art, Ait, (float2*)d_out);
}

// Round 6
// 105.325 us; speedup vs baseline: 1.0128x; 1.0128x over previous
//
#include <hip/hip_runtime.h>
#include <hip/hip_bf16.h>

#define N_Q    20
#define DIM    (1 << N_Q)      // 1048576
#define BATCH  4
#define NGATES 19
#define L2OFF  117             // 6n-3 : second xyz layer offset

typedef float2 c32;
typedef __attribute__((ext_vector_type(8))) short short8;
typedef __attribute__((ext_vector_type(4))) float f32x4;
typedef __attribute__((ext_vector_type(4))) unsigned int u32x4;

__device__ __forceinline__ c32 cmul(c32 a, c32 b) {
    return make_float2(fmaf(a.x, b.x, -a.y * b.y), fmaf(a.x, b.y, a.y * b.x));
}
__device__ __forceinline__ c32 cmadd(c32 acc, c32 a, c32 b) {
    acc.x = fmaf(a.x, b.x, fmaf(-a.y, b.y, acc.x));
    acc.y = fmaf(a.x, b.y, fmaf(a.y, b.x, acc.y));
    return acc;
}
__device__ __forceinline__ unsigned short f2bf(float f) {
    union { float f; unsigned u; } v; v.f = f;
    unsigned r = v.u + 0x7FFFu + ((v.u >> 16) & 1u);
    return (unsigned short)(r >> 16);
}
__device__ __forceinline__ void gll16(const void* g, void* l) {
    __builtin_amdgcn_global_load_lds((const __attribute__((address_space(1))) void*)g,
                                     (__attribute__((address_space(3))) void*)l, 16, 0, 0);
}

__device__ void mm2(const c32 A[2][2], const c32 B[2][2], c32 C[2][2]) {
    for (int i = 0; i < 2; i++)
        for (int j = 0; j < 2; j++) {
            c32 s = make_float2(0.f, 0.f);
            for (int k = 0; k < 2; k++) s = cmadd(s, A[i][k], B[k][j]);
            C[i][j] = s;
        }
}
__device__ void mm4(const c32 A[4][4], const c32 B[4][4], c32 C[4][4]) {
    for (int i = 0; i < 4; i++)
        for (int j = 0; j < 4; j++) {
            c32 s = make_float2(0.f, 0.f);
            for (int k = 0; k < 4; k++) s = cmadd(s, A[i][k], B[k][j]);
            C[i][j] = s;
        }
}
__device__ void single_u(const float* w, int base, c32 U[2][2]) {
    const float WM = 0.63245553203367586640f;  // sqrt(2/5)
    float hx = w[base] * WM * 0.5f, hy = w[base + 1] * WM * 0.5f, hz = w[base + 2] * WM * 0.5f;
    float cx = cosf(hx), sx = sinf(hx);
    float cy = cosf(hy), sy = sinf(hy);
    float cz = cosf(hz), sz = sinf(hz);
    c32 RX[2][2] = {{{cx, 0.f}, {0.f, -sx}}, {{0.f, -sx}, {cx, 0.f}}};
    c32 RY[2][2] = {{{cy, 0.f}, {-sy, 0.f}}, {{sy, 0.f}, {cy, 0.f}}};
    c32 RZ[2][2] = {{{cz, -sz}, {0.f, 0.f}}, {{0.f, 0.f}, {cz, sz}}};
    c32 T[2][2];
    mm2(RY, RX, T);
    mm2(RZ, T, U);
}
__device__ void kron22(const c32 A[2][2], const c32 B[2][2], c32 K[4][4]) {
    for (int i = 0; i < 2; i++)
        for (int j = 0; j < 2; j++)
            for (int k = 0; k < 2; k++)
                for (int l = 0; l < 2; l++)
                    K[i * 2 + j][k * 2 + l] = cmul(A[i][k], B[j][l]);
}

// Build the 19 fused 4x4 staircase gates (round-0 derivation).
__global__ void build_gates(const float* __restrict__ w, c32* __restrict__ G) {
    int q = threadIdx.x;
    if (q >= NGATES) return;
    const float WM = 0.63245553203367586640f;
    float hx = w[60 + 3 * q] * WM * 0.5f;
    float hy = w[61 + 3 * q] * WM * 0.5f;
    float hz = w[62 + 3 * q] * WM * 0.5f;
    float cx = cosf(hx), sx = sinf(hx);
    float cy = cosf(hy), sy = sinf(hy);
    float cz = cosf(hz), sz = sinf(hz);
    c32 RXX[4][4], RYY[4][4], RZZ[4][4];
    for (int i = 0; i < 4; i++)
        for (int j = 0; j < 4; j++) {
            RXX[i][j] = make_float2(0.f, 0.f);
            RYY[i][j] = make_float2(0.f, 0.f);
            RZZ[i][j] = make_float2(0.f, 0.f);
        }
    for (int i = 0; i < 4; i++) {
        RXX[i][i]     = make_float2(cx, 0.f);
        RXX[i][3 - i] = make_float2(0.f, -sx);
        RYY[i][i]     = make_float2(cy, 0.f);
    }
    RYY[0][3] = make_float2(0.f,  sy);
    RYY[1][2] = make_float2(0.f, -sy);
    RYY[2][1] = make_float2(0.f, -sy);
    RYY[3][0] = make_float2(0.f,  sy);
    RZZ[0][0] = make_float2(cz, -sz);
    RZZ[1][1] = make_float2(cz,  sz);
    RZZ[2][2] = make_float2(cz,  sz);
    RZZ[3][3] = make_float2(cz, -sz);
    c32 T[4][4], M[4][4];
    mm4(RYY, RXX, T);
    mm4(RZZ, T, M);

    c32 I2m[2][2] = {{{1.f, 0.f}, {0.f, 0.f}}, {{0.f, 0.f}, {1.f, 0.f}}};
    c32 Ua[2][2], Ub[2][2], Pre[4][4], Post[4][4];
    if (q == 0) {
        single_u(w, 0, Ua);
        single_u(w, 3, Ub);
        kron22(Ua, Ub, Pre);
    } else {
        single_u(w, 3 * (q + 1), Ub);
        kron22(I2m, Ub, Pre);
    }
    if (q == NGATES - 1) {
        single_u(w, L2OFF + 3 * 18, Ua);
        single_u(w, L2OFF + 3 * 19, Ub);
        kron22(Ua, Ub, Post);
    } else {
        single_u(w, L2OFF + 3 * q, Ua);
        kron22(Ua, I2m, Post);
    }
    c32 T2[4][4], Gq[4][4];
    mm4(M, Pre, T2);
    mm4(Post, T2, Gq);
    for (int i = 0; i < 4; i++)
        for (int j = 0; j < 4; j++)
            G[q * 16 + i * 4 + j] = Gq[i][j];
}

__device__ __forceinline__ void apply4(const c32* g, c32& x0, c32& x1, c32& x2, c32& x3) {
    c32 r0 = cmul(g[0],  x0); r0 = cmadd(r0, g[1],  x1); r0 = cmadd(r0, g[2],  x2); r0 = cmadd(r0, g[3],  x3);
    c32 r1 = cmul(g[4],  x0); r1 = cmadd(r1, g[5],  x1); r1 = cmadd(r1, g[6],  x2); r1 = cmadd(r1, g[7],  x3);
    c32 r2 = cmul(g[8],  x0); r2 = cmadd(r2, g[9],  x1); r2 = cmadd(r2, g[10], x2); r2 = cmadd(r2, g[11], x3);
    c32 r3 = cmul(g[12], x0); r3 = cmadd(r3, g[13], x1); r3 = cmadd(r3, g[14], x2); r3 = cmadd(r3, g[15], x3);
    x0 = r0; x1 = r1; x2 = r2; x3 = r3;
}
__device__ __forceinline__ void load_gate(const c32* __restrict__ gp, c32 g[16]) {
#pragma unroll
    for (int k = 0; k < 16; k++) g[k] = gp[k];
}
template <int LO>
__device__ __forceinline__ void gate_on32(c32 v[32], const c32 g[16]) {
#pragma unroll
    for (int m = 0; m < 8; ++m) {
        const int j0 = ((m >> LO) << (LO + 2)) | (m & ((1 << LO) - 1));
        const int s = 1 << LO;
        apply4(g, v[j0], v[j0 + s], v[j0 + 2 * s], v[j0 + 3 * s]);
    }
}
template <int LO>
__device__ __forceinline__ void gate_on16(c32* v, const c32 g[16]) {
#pragma unroll
    for (int m = 0; m < 4; ++m) {
        const int j0 = ((m >> LO) << (LO + 2)) | (m & ((1 << LO) - 1));
        const int s = 1 << LO;
        apply4(g, v[j0], v[j0 + s], v[j0 + 2 * s], v[j0 + 3 * s]);
    }
}

// XOR swizzle for 8192-c32 LDS exchanges (verified <=4-way for all patterns used).
#define SIDX(l) ((l) ^ ((((l) >> 5) & 15)))

// Pass A2: gates 0..6 (psi bits 19..12). State = [256 rows = bits 19..12][4096 cols].
__global__ __launch_bounds__(256) void pass_a2(const float* __restrict__ x,
                                               c32* __restrict__ psi,
                                               const c32* __restrict__ Gall) {
    __shared__ __align__(16) char smem[65536];
    float* xs = (float*)smem;        // [256][32] f32, 16B-slot swizzled (32 KB)
    c32* s = (c32*)smem;             // 8192 c32 exchange view (64 KB)
    int b = blockIdx.x >> 7;
    int c0 = (blockIdx.x & 127) << 5;
    const float* xp = x + ((size_t)b << 20) + c0;
    c32* pp = psi + ((size_t)b << 20) + c0;
    int t = threadIdx.x;
#pragma unroll
    for (int i = 0; i < 8; ++i) {
        int f4 = t + (i << 8);
        int row = f4 >> 3, sl = f4 & 7;
        float4 v = *reinterpret_cast<const float4*>(xp + (size_t)row * 4096 + sl * 4);
        reinterpret_cast<float4*>(xs)[row * 8 + (sl ^ (row & 7))] = v;
    }
    __syncthreads();
    int col = t & 31, rlow = t >> 5;
    c32 v[32], g[16];
#pragma unroll
    for (int j = 0; j < 32; ++j) {
        int row = (j << 3) | rlow;
        float re = xs[row * 32 + ((((col >> 2) ^ (row & 7)) << 2) | (col & 3))];
        v[j] = make_float2(re, 0.f);
    }
    __syncthreads();
    load_gate(Gall + 0 * 16, g);  gate_on32<3>(v, g);
    load_gate(Gall + 1 * 16, g);  gate_on32<2>(v, g);
    load_gate(Gall + 2 * 16, g);  gate_on32<1>(v, g);
    load_gate(Gall + 3 * 16, g);  gate_on32<0>(v, g);
#pragma unroll
    for (int j = 0; j < 32; ++j) {
        int l = ((((j << 3) | rlow) << 5)) | col;
        s[SIDX(l)] = v[j];
    }
    __syncthreads();
    int rhi = t >> 5;
#pragma unroll
    for (int rtop = 0; rtop < 2; ++rtop)
#pragma unroll
        for (int j = 0; j < 16; ++j) {
            int row = (rtop << 7) | (rhi << 4) | j;
            int l = (row << 5) | col;
            v[rtop * 16 + j] = s[SIDX(l)];
        }
    load_gate(Gall + 4 * 16, g);  gate_on16<2>(v, g);  gate_on16<2>(v + 16, g);
    load_gate(Gall + 5 * 16, g);  gate_on16<1>(v, g);  gate_on16<1>(v + 16, g);
    load_gate(Gall + 6 * 16, g);  gate_on16<0>(v, g);  gate_on16<0>(v + 16, g);
#pragma unroll
    for (int rtop = 0; rtop < 2; ++rtop)
#pragma unroll
        for (int j = 0; j < 16; ++j) {
            int row = (rtop << 7) | (rhi << 4) | j;
            pp[(size_t)row * 4096 + col] = v[rtop * 16 + j];
        }
}

// Pass B2: gates 7..18 (psi bits 12..0). 3 register phases, 2 LDS exchanges;
// writes planar bf16 [t][a] (Brt, Bit).
__global__ __launch_bounds__(256) void pass_b2(const c32* __restrict__ psi,
                                               unsigned short* __restrict__ Brt,
                                               unsigned short* __restrict__ Bit,
                                               const c32* __restrict__ Gall) {
    __shared__ c32 s[8192];
    int b = blockIdx.x >> 7;
    int chunk = blockIdx.x & 127;
    const c32* pp = psi + ((size_t)b << 20) + ((size_t)chunk << 13);
    int t = threadIdx.x;
    c32 v[32], g[16];
#pragma unroll
    for (int j = 0; j < 32; ++j) v[j] = pp[(j << 8) | t];
    load_gate(Gall + 7 * 16, g);   gate_on32<3>(v, g);
    load_gate(Gall + 8 * 16, g);   gate_on32<2>(v, g);
    load_gate(Gall + 9 * 16, g);   gate_on32<1>(v, g);
    load_gate(Gall + 10 * 16, g);  gate_on32<0>(v, g);
#pragma unroll
    for (int j = 0; j < 32; ++j) { int l = (j << 8) | t; s[SIDX(l)] = v[j]; }
    __syncthreads();
    int hi2 = (t >> 4) << 9, lo2 = t & 15;
#pragma unroll
    for (int j = 0; j < 32; ++j) { int l = hi2 | (j << 4) | lo2; v[j] = s[SIDX(l)]; }
    load_gate(Gall + 11 * 16, g);  gate_on32<3>(v, g);
    load_gate(Gall + 12 * 16, g);  gate_on32<2>(v, g);
    load_gate(Gall + 13 * 16, g);  gate_on32<1>(v, g);
    load_gate(Gall + 14 * 16, g);  gate_on32<0>(v, g);
    __syncthreads();
#pragma unroll
    for (int j = 0; j < 32; ++j) { int l = hi2 | (j << 4) | lo2; s[SIDX(l)] = v[j]; }
    __syncthreads();
#pragma unroll
    for (int j = 0; j < 32; ++j) { int l = (t << 5) | j; v[j] = s[SIDX(l)]; }
    load_gate(Gall + 15 * 16, g);  gate_on32<3>(v, g);
    load_gate(Gall + 16 * 16, g);  gate_on32<2>(v, g);
    load_gate(Gall + 17 * 16, g);  gate_on32<1>(v, g);
    load_gate(Gall + 18 * 16, g);  gate_on32<0>(v, g);
    size_t off = ((size_t)b << 20) + ((size_t)chunk << 13) + ((size_t)t << 5);
#pragma unroll
    for (int p = 0; p < 4; ++p) {
        unsigned short rr[8], ri[8];
#pragma unroll
        for (int i = 0; i < 8; ++i) {
            rr[i] = f2bf(v[8 * p + i].x);
            ri[i] = f2bf(v[8 * p + i].y);
        }
        *reinterpret_cast<float4*>(Brt + off + 8 * p) = *reinterpret_cast<float4*>(rr);
        *reinterpret_cast<float4*>(Bit + off + 8 * p) = *reinterpret_cast<float4*>(ri);
    }
}

// bf16 transpose: B[t][a] -> A[a][t] for both planes, merged as u32 in LDS.
__global__ __launch_bounds__(256) void bt_t(const unsigned short* __restrict__ Brt,
                                            const unsigned short* __restrict__ Bit,
                                            unsigned short* __restrict__ Art,
                                            unsigned short* __restrict__ Ait) {
    __shared__ unsigned lds32[64 * 66];
    int b  = blockIdx.z;
    int t0 = blockIdx.x * 64;
    int a0 = blockIdx.y * 64;
    size_t gb = (size_t)b << 20;
#pragma unroll
    for (int h = 0; h < 2; ++h) {
        int p = threadIdx.x + h * 256;
        int r = p >> 3, cq = p & 7;
        size_t src = gb + (size_t)(t0 + r) * 1024 + a0 + cq * 8;
        float4 fr = *reinterpret_cast<const float4*>(Brt + src);
        float4 fi = *reinterpret_cast<const float4*>(Bit + src);
        const unsigned short* ur = reinterpret_cast<const unsigned short*>(&fr);
        const unsigned short* ui = reinterpret_cast<const unsigned short*>(&fi);
#pragma unroll
        for (int i = 0; i < 8; ++i)
            lds32[r * 66 + cq * 8 + i] = (unsigned)ur[i] | ((unsigned)ui[i] << 16);
    }
    __syncthreads();
#pragma unroll
    for (int h = 0; h < 2; ++h) {
        int q = threadIdx.x + h * 256;
        int a = q >> 3, tq = q & 7;
        unsigned short rr[8], ri[8];
#pragma unroll
        for (int i = 0; i < 8; ++i) {
            unsigned w = lds32[(tq * 8 + i) * 66 + a];
            rr[i] = (unsigned short)(w & 0xFFFF);
            ri[i] = (unsigned short)(w >> 16);
        }
        size_t dst = gb + (size_t)(a0 + a) * 1024 + t0 + tq * 8;
        *reinterpret_cast<float4*>(Art + dst) = *reinterpret_cast<float4*>(rr);
        *reinterpret_cast<float4*>(Ait + dst) = *reinterpret_cast<float4*>(ri);
    }
}

// gram_mfma3: counted-vmcnt raw-barrier pipeline (T4). Per K-step:
//   STAGE(kt+1) -> s_waitcnt vmcnt(8) -> s_barrier -> ds_read+MFMA
//   -> s_waitcnt lgkmcnt(0) -> s_barrier
// The 8 gll loads for kt+1 stay in flight across the barrier (never drain to 0
// in the loop) -- removes the per-step load-latency stall of __syncthreads().
__device__ __forceinline__ void stage_panel(const unsigned short* __restrict__ sp, size_t gb,
                                            int prow, int kt, unsigned short* dst, int lane) {
    int srow = lane >> 3, sslot = lane & 7;
#pragma unroll
    for (int i = 0; i < 8; ++i) {
        int r = (i << 3) | srow;
        int sl = sslot ^ srow;             // (r&7) == srow
        const unsigned short* gp = sp + gb + ((size_t)(prow + r) << 10) + kt * 64 + sl * 8;
        gll16(gp, dst + i * 512);          // linear dest: base + lane*16B
    }
}
__global__ __launch_bounds__(256) void gram_mfma3(const unsigned short* __restrict__ Art,
                                                  const unsigned short* __restrict__ Ait,
                                                  float2* __restrict__ out) {
    __shared__ unsigned short lds[2][4][4096];   // 64 KB
    int b = blockIdx.y;
    int rem = blockIdx.x;                        // triangular decode, ia <= ic
    int ia = 0;
    while (rem >= 16 - ia) { rem -= 16 - ia; ++ia; }
    int ic = ia + rem;
    int a0 = ia * 64, c0 = ic * 64;
    int lane = threadIdx.x & 63, w = threadIdx.x >> 6;
    int wr = (w >> 1) * 32, wc = (w & 1) * 32;
    const unsigned short* sp = (w & 1) ? Ait : Art;   // wave stages one array
    int prow = (w < 2) ? a0 : c0;
    size_t gb = (size_t)b << 20;

    f32x4 accRe[2][2], accIm[2][2];
#pragma unroll
    for (int m = 0; m < 2; m++)
#pragma unroll
        for (int n = 0; n < 2; n++) { accRe[m][n] = (f32x4)0.f; accIm[m][n] = (f32x4)0.f; }

    stage_panel(sp, gb, prow, 0, &lds[0][w][0], lane);
    for (int kt = 0; kt < 16; ++kt) {
        int cur = kt & 1;
        if (kt < 15) {
            stage_panel(sp, gb, prow, kt + 1, &lds[cur ^ 1][w][0], lane);
            asm volatile("s_waitcnt vmcnt(8)" ::: "memory");   // kt's 8 loads retired
        } else {
            asm volatile("s_waitcnt vmcnt(0)" ::: "memory");   // last tile: drain
        }
        __builtin_amdgcn_s_barrier();                          // all waves' panels landed
        __builtin_amdgcn_sched_barrier(0);
#pragma unroll
        for (int kk = 0; kk < 2; ++kk) {
            int sbase = kk * 4 + (lane >> 4);    // 16B-slot index 0..7
            short8 ar[2], ai[2], br[2], bi[2];
#pragma unroll
            for (int m = 0; m < 2; m++) {
                int r = wr + m * 16 + (lane & 15);
                int off = r * 64 + ((sbase ^ (r & 7)) << 3);
                ar[m] = *reinterpret_cast<const short8*>(&lds[cur][0][off]);
                ai[m] = *reinterpret_cast<const short8*>(&lds[cur][1][off]);
            }
#pragma unroll
            for (int n = 0; n < 2; n++) {
                int r = wc + n * 16 + (lane & 15);
                int off = r * 64 + ((sbase ^ (r & 7)) << 3);
                br[n] = *reinterpret_cast<const short8*>(&lds[cur][2][off]);
                bi[n] = *reinterpret_cast<const short8*>(&lds[cur][3][off]);
            }
#pragma unroll
            for (int m = 0; m < 2; m++) {
                u32x4 tn = *reinterpret_cast<u32x4*>(&ar[m]) ^ 0x80008000u;
                short8 arn = *reinterpret_cast<short8*>(&tn);
#pragma unroll
                for (int n = 0; n < 2; n++) {
                    accRe[m][n] = __builtin_amdgcn_mfma_f32_16x16x32_bf16(ar[m],  br[n], accRe[m][n], 0, 0, 0);
                    accRe[m][n] = __builtin_amdgcn_mfma_f32_16x16x32_bf16(ai[m],  bi[n], accRe[m][n], 0, 0, 0);
                    accIm[m][n] = __builtin_amdgcn_mfma_f32_16x16x32_bf16(ai[m],  br[n], accIm[m][n], 0, 0, 0);
                    accIm[m][n] = __builtin_amdgcn_mfma_f32_16x16x32_bf16(arn,    bi[n], accIm[m][n], 0, 0, 0);
                }
            }
        }
        asm volatile("s_waitcnt lgkmcnt(0)" ::: "memory");     // my buf[cur] reads retired
        __builtin_amdgcn_sched_barrier(0);
        __builtin_amdgcn_s_barrier();                          // safe to overwrite buf[cur]
        __builtin_amdgcn_sched_barrier(0);
    }
    // C/D layout: col = lane&15, row = (lane>>4)*4 + reg
    size_t ob = (size_t)b << 20;
#pragma unroll
    for (int m = 0; m < 2; m++)
#pragma unroll
        for (int n = 0; n < 2; n++)
#pragma unroll
            for (int r = 0; r < 4; r++) {
                int a = a0 + wr + m * 16 + (lane >> 4) * 4 + r;
                int c = c0 + wc + n * 16 + (lane & 15);
                float re = accRe[m][n][r];
                float im = accIm[m][n][r];
                out[ob + ((size_t)a << 10) + c] = make_float2(re, im);
                if (ia != ic)
                    out[ob + ((size_t)c << 10) + a] = make_float2(re, -im);
            }
}

extern "C" void kernel_launch(void* const* d_in, const int* in_sizes, int n_in,
                              void* d_out, int out_size, void* d_ws, size_t ws_size,
                              hipStream_t stream) {
    const float* x = (const float*)d_in[0];
    const float* weight = (const float*)d_in[1];
    const size_t psiBytes = (size_t)BATCH * DIM * sizeof(c32);       // 32 MB
    c32* psi = (c32*)d_ws;
    c32* G = (c32*)((char*)d_ws + psiBytes);
    unsigned short* Brt = (unsigned short*)((char*)d_ws + psiBytes + 65536);
    unsigned short* Bit = Brt + (size_t)BATCH * DIM;
    unsigned short* Art = Bit + (size_t)BATCH * DIM;
    unsigned short* Ait = Art + (size_t)BATCH * DIM;

    build_gates<<<1, 64, 0, stream>>>(weight, G);
    pass_a2<<<BATCH * 128, 256, 0, stream>>>(x, psi, G);            // gates 0..6
    pass_b2<<<BATCH * 128, 256, 0, stream>>>(psi, Brt, Bit, G);     // gates 7..18 -> bf16 [t][a]
    bt_t<<<dim3(16, 16, BATCH), 256, 0, stream>>>(Brt, Bit, Art, Ait);
    gram_mfma3<<<dim3(136, BATCH), 256, 0, stream>>>(Art, Ait, (float2*)d_out);
}